// Round 5
// baseline (352.881 us; speedup 1.0000x reference)
//
#include <hip/hip_runtime.h>
#include <hip/hip_bf16.h>

// DecoderLayer cross-attention, MI355X/gfx950. Round 8.
// B=4, Sq=2048, Skv=4096, D=512. fp32 in/out, bf16 MFMA internally.
// R8 changes vs R7 (LDS-port bound: Kt reads 256/tile @ ~12cyc + 4.5cyc conflicts each):
//  - QK wave split (qh=w>>2, cw=w&3): 32 q-rows x 16 kv-cols per wave. Q regs af[2][16]
//    (128 VGPR), each Kt B-frag feeds 2 MFMAs -> Kt reads halve (256->128 instr/tile).
//  - 4-bit XOR swizzle (l15<<4): every 8/16-lane phase covers all 16 slots -> conflict-free.
//  - mid-tile barrier = lgkmcnt(0)-only (raw s_barrier): K-DMA prefetch stays in flight a
//    full tile (was drained by __syncthreads vmcnt(0) mid-tile). vf issued before DMA.
// ws layout:
//   Qb  bf16 [8192][512]          @ 0           (8,388,608)
//   Kb  bf16 [16384][512]         @ 8,388,608   (16,777,216)
//   Vtg bf16 [4][128][512][32]    @ 25,165,824  (16,777,216)   (t-tiled)
//   region B @ 41,943,040:
//     phase1: xb 8.4M | encb @+8.4M 16.8M | wqb/wkb/wvb @+25.2M 0.5M each
//     phase2: Op f32 [2][8192][512] | lp f32 [2][8192]  (need 75,563,008 B)

typedef __bf16 bf16;
typedef __attribute__((ext_vector_type(8))) __bf16 bf16x8;
typedef __attribute__((ext_vector_type(4))) float f32x4;

#define DM 512

__device__ __forceinline__ void gload_lds16(const bf16* g, bf16* l)
{
    __builtin_amdgcn_global_load_lds(
        (const __attribute__((address_space(1))) void*)g,
        (__attribute__((address_space(3))) void*)l, 16, 0, 0);
}

// ---------------- fp32 -> bf16 convert prepass (single launch, 5 regions) -----------------
__global__ __launch_bounds__(256) void cvt_all_kernel(
    const float* __restrict__ x,   bf16* __restrict__ xb,
    const float* __restrict__ enc, bf16* __restrict__ encb,
    const float* __restrict__ wq,  bf16* __restrict__ wqb,
    const float* __restrict__ wk,  bf16* __restrict__ wkb,
    const float* __restrict__ wv,  bf16* __restrict__ wvb)
{
    int g = blockIdx.x * 256 + threadIdx.x;
    const float* src; bf16* dst;
    if (g < 524288)       { src = x;   dst = xb; }
    else if (g < 1572864) { g -= 524288;  src = enc; dst = encb; }
    else if (g < 1605632) { g -= 1572864; src = wq;  dst = wqb; }
    else if (g < 1638400) { g -= 1605632; src = wk;  dst = wkb; }
    else                  { g -= 1638400; src = wv;  dst = wvb; }
    const float4 f0 = *reinterpret_cast<const float4*>(src + (size_t)g * 8);
    const float4 f1 = *reinterpret_cast<const float4*>(src + (size_t)g * 8 + 4);
    bf16x8 v;
    v[0]=(bf16)f0.x; v[1]=(bf16)f0.y; v[2]=(bf16)f0.z; v[3]=(bf16)f0.w;
    v[4]=(bf16)f1.x; v[5]=(bf16)f1.y; v[6]=(bf16)f1.z; v[7]=(bf16)f1.w;
    *reinterpret_cast<bf16x8*>(dst + (size_t)g * 8) = v;
}

// ---------------- Projection GEMMs (bf16 in): out = A @ W^T + b, stored bf16 ---------------
// KV=false: Q row-major. KV=true: K row-major + V t-tiled Vtg[b][t>>5][e][t&31].
template<bool KV>
__global__ __launch_bounds__(256) void proj_kernel(const bf16* __restrict__ A,
    const bf16* __restrict__ W0, const float* __restrict__ b0, bf16* __restrict__ out0,
    const bf16* __restrict__ W1, const float* __restrict__ b1, bf16* __restrict__ out1)
{
    __shared__ __align__(16) bf16 As[2][64][40];
    __shared__ __align__(16) bf16 W0s[2][64][40];
    __shared__ __align__(16) bf16 W1s[2][64][40];

    const int tid  = threadIdx.x;
    const int w    = tid >> 6, lane = tid & 63, quad = lane >> 4, l15 = lane & 15;
    const int wr   = w >> 1, wc = w & 1;
    const int n0   = blockIdx.x * 64;
    const int m0   = blockIdx.y * 64;
    const int srow = tid >> 2;
    const int scol = (tid & 3) * 8;

    f32x4 acc0[2][2] = {}, acc1[2][2] = {};
    bf16x8 ra, rw0, rw1;

    auto prefetch = [&](int kk) {
        ra  = *reinterpret_cast<const bf16x8*>(A  + (size_t)(m0 + srow) * DM + kk + scol);
        rw0 = *reinterpret_cast<const bf16x8*>(W0 + (size_t)(n0 + srow) * DM + kk + scol);
        if constexpr (KV)
            rw1 = *reinterpret_cast<const bf16x8*>(W1 + (size_t)(n0 + srow) * DM + kk + scol);
    };
    auto store_lds = [&](int p) {
        *reinterpret_cast<bf16x8*>(&As[p][srow][scol])  = ra;
        *reinterpret_cast<bf16x8*>(&W0s[p][srow][scol]) = rw0;
        if constexpr (KV)
            *reinterpret_cast<bf16x8*>(&W1s[p][srow][scol]) = rw1;
    };

    prefetch(0);
    store_lds(0);
    __syncthreads();

    for (int step = 0; step < 16; step++) {
        const int p = step & 1;
        if (step < 15) prefetch((step + 1) * 32);

        bf16x8 af[2], bf0[2], bf1[2];
#pragma unroll
        for (int mt = 0; mt < 2; mt++)
            af[mt] = *reinterpret_cast<const bf16x8*>(&As[p][32*wr + 16*mt + l15][quad*8]);
#pragma unroll
        for (int nt = 0; nt < 2; nt++)
            bf0[nt] = *reinterpret_cast<const bf16x8*>(&W0s[p][32*wc + 16*nt + l15][quad*8]);
        if constexpr (KV) {
#pragma unroll
            for (int nt = 0; nt < 2; nt++)
                bf1[nt] = *reinterpret_cast<const bf16x8*>(&W1s[p][32*wc + 16*nt + l15][quad*8]);
        }
#pragma unroll
        for (int mt = 0; mt < 2; mt++)
#pragma unroll
            for (int nt = 0; nt < 2; nt++) {
                acc0[mt][nt] = __builtin_amdgcn_mfma_f32_16x16x32_bf16(af[mt], bf0[nt], acc0[mt][nt], 0, 0, 0);
                if constexpr (KV)
                    acc1[mt][nt] = __builtin_amdgcn_mfma_f32_16x16x32_bf16(af[mt], bf1[nt], acc1[mt][nt], 0, 0, 0);
            }

        if (step < 15) store_lds(p ^ 1);
        __syncthreads();
    }

#pragma unroll
    for (int mt = 0; mt < 2; mt++)
#pragma unroll
        for (int nt = 0; nt < 2; nt++) {
            const int coll = 32*wc + 16*nt + l15;
            const int rowl = 32*wr + 16*mt + quad*4;
            {
                const float bv = b0[n0 + coll];
                f32x4 c = acc0[mt][nt];
#pragma unroll
                for (int r = 0; r < 4; r++)
                    out0[(size_t)(m0 + rowl + r) * DM + n0 + coll] = (bf16)(c[r] + bv);
            }
            if constexpr (KV) {
                const float bv = b1[n0 + coll];
                f32x4 c = acc1[mt][nt];
                const int gr = m0 + rowl;
                const int bidx = gr >> 12, t = gr & 4095;
                const int e = n0 + coll;
                union { uint2 u; bf16 h[4]; } pk;
#pragma unroll
                for (int r = 0; r < 4; r++) pk.h[r] = (bf16)(c[r] + bv);
                // t-tiled: Vtg[bidx][t>>5][e][t&31], t % 4 == 0 -> 4 contiguous elems
                *reinterpret_cast<uint2*>(out1 +
                    ((((size_t)(bidx*128 + (t >> 5)) * DM + e) << 5) + (t & 31))) = pk.u;
            }
        }
}

// ---------------- Fused attention: LDS-K (swz), reg-Q (32 rows/wave), reg-V ----------------
// 512 threads / 8 waves, 1 block/CU, grid 256 = 1 round.
// QK: wave (qh=w>>2, cw=w&3): S[32qh..+32][16cw..+16]; A = Q regs af[2][16], B = Kt LDS.
//     Each B-frag feeds 2 MFMAs (mt=0,1) -> 128 Kt reads/tile (was 256).
// PV: wave w: O[64 q][64 e cols 64w..]; A = Ps LDS, B = V regs (t-tiled contiguous loads).
__global__ __launch_bounds__(512, 2) void attn_kernel(const bf16* __restrict__ Qb,
                                                      const bf16* __restrict__ Kb,
                                                      const bf16* __restrict__ Vtg,
                                                      float* __restrict__ Op,
                                                      float* __restrict__ lp)
{
    __shared__ __align__(16) bf16 Kt[2][64][512];   // 131,072 B; 4-bit XOR swizzle (src-side)
    __shared__ __align__(16) bf16 Ps[64][80];       //  10,240 B; 40 dw stride
    __shared__ float lred[64];

    const int tid  = threadIdx.x;
    const int w    = tid >> 6, lane = tid & 63, quad = lane >> 4, l15 = lane & 15;
    const int qh   = w >> 2;                 // QK q-row half 0..1
    const int cw   = w & 3;                  // QK kv col group 0..3

    // XCD-swizzle: 8 (b,z) combos map 1:1 onto 8 XCDs.
    const int id = blockIdx.x;               // 256 blocks
    const int combo = id & 7, qblk = id >> 3;
    const int b = combo & 3, z = combo >> 2;
    const int q0 = qblk * 64;
    const int NT = 32, tb = z * 2048;        // 32 tiles of 64 kv rows

    // ---- Q A-fragments into registers: af[mt][k4], rows 32qh+16mt+l15 (128 VGPR) ----
    bf16x8 af[2][16];
#pragma unroll
    for (int mt = 0; mt < 2; mt++) {
        const bf16* qsrc = Qb + (size_t)(b*2048 + q0 + 32*qh + 16*mt + l15) * DM + quad*8;
#pragma unroll
        for (int k4 = 0; k4 < 16; k4++)
            af[mt][k4] = *reinterpret_cast<const bf16x8*>(qsrc + k4*32);
    }
    if (tid < 64) lred[tid] = 0.f;

    const bf16* kbase = Kb + (size_t)(b*4096 + tb) * DM;
    // ---- stage K tile 0 (1 contiguous 1KB row/instr; source lane 4-bit XOR) ----
#pragma unroll
    for (int i = 0; i < 8; i++) {
        const int row = w + 8*i;             // row & 7 == w
        gload_lds16(kbase + (size_t)row * DM + ((lane ^ (row & 15)) * 8), &Kt[0][row][0]);
    }
    __syncthreads();                          // drains DMA, publishes lred

    f32x4 oacc[4][4] = {};
    float lsum[2][4] = {};
    const float kexp = 1.44269504088896f * 0.044194173824159216f;  // log2(e)/sqrt(512)
    const int sxor = l15 << 4;                // read-side 4-bit XOR (row&15 == l15)

    for (int t = 0; t < NT; t++) {
        const int buf = t & 1;

        // V fragments for THIS tile first (oldest vmcnt -> PV's vf-wait won't drain DMA)
        bf16x8 vf[4][2];
#pragma unroll
        for (int ks = 0; ks < 2; ks++) {
            const size_t tblk = (size_t)(b*128 + z*64 + t*2 + ks) * DM;
#pragma unroll
            for (int nt = 0; nt < 4; nt++)
                vf[nt][ks] = *reinterpret_cast<const bf16x8*>(
                    Vtg + ((tblk + 64*w + 16*nt + l15) << 5) + quad*8);
        }

        // prefetch next K tile (stays in flight until end-of-tile __syncthreads)
        if (t + 1 < NT) {
            const bf16* ksrc = kbase + (size_t)(t + 1) * 64 * DM;
#pragma unroll
            for (int i = 0; i < 8; i++) {
                const int row = w + 8*i;
                gload_lds16(ksrc + (size_t)row * DM + ((lane ^ (row & 15)) * 8), &Kt[buf ^ 1][row][0]);
            }
        }

        // ---- QK: S[32qh..+32][16cw..+16], A regs x B LDS (B-frag reused for 2 mt) ----
        f32x4 sacc[2] = {};
        const char* krow = (const char*)&Kt[buf][16*cw + l15][0];
#pragma unroll
        for (int k4 = 0; k4 < 16; k4++) {
            const int off = (k4*64 + quad*16) ^ sxor;
            bf16x8 kf = *reinterpret_cast<const bf16x8*>(krow + off);
            sacc[0] = __builtin_amdgcn_mfma_f32_16x16x32_bf16(af[0][k4], kf, sacc[0], 0, 0, 0);
            sacc[1] = __builtin_amdgcn_mfma_f32_16x16x32_bf16(af[1][k4], kf, sacc[1], 0, 0, 0);
        }

        // exp -> Ps (C-layout -> A-layout), accumulate l
#pragma unroll
        for (int mt = 0; mt < 2; mt++)
#pragma unroll
            for (int r = 0; r < 4; r++) {
                const float p = exp2f(sacc[mt][r] * kexp);
                lsum[mt][r] += p;
                Ps[32*qh + 16*mt + quad*4 + r][16*cw + l15] = (bf16)p;
            }

        // mid-tile barrier: lgkm-only (Ps is DS traffic; keep K-DMA in flight)
        asm volatile("s_waitcnt lgkmcnt(0)" ::: "memory");
        __builtin_amdgcn_s_barrier();
        __builtin_amdgcn_sched_barrier(0);

        // ---- PV: O[64][64w..+64] += P[64][64] * V[64][...], A LDS x B regs ----
#pragma unroll
        for (int ks = 0; ks < 2; ks++) {
            bf16x8 ap[4];
#pragma unroll
            for (int mt = 0; mt < 4; mt++)
                ap[mt] = *reinterpret_cast<const bf16x8*>(&Ps[16*mt + l15][ks*32 + quad*8]);
#pragma unroll
            for (int nt = 0; nt < 4; nt++)
#pragma unroll
                for (int mt = 0; mt < 4; mt++)
                    oacc[mt][nt] = __builtin_amdgcn_mfma_f32_16x16x32_bf16(ap[mt], vf[nt][ks], oacc[mt][nt], 0, 0, 0);
        }
        __syncthreads();                      // protect Ps + publish K-DMA for next tile
    }

    // ---- epilogue: l reduction + O partial write ----
#pragma unroll
    for (int mt = 0; mt < 2; mt++)
#pragma unroll
        for (int r = 0; r < 4; r++)
            atomicAdd(&lred[32*qh + 16*mt + quad*4 + r], lsum[mt][r]);
    __syncthreads();

    if (tid < 64) lp[(size_t)z * 8192 + b * 2048 + q0 + tid] = lred[tid];
#pragma unroll
    for (int mt = 0; mt < 4; mt++)
#pragma unroll
        for (int r = 0; r < 4; r++) {
            const int row = 16*mt + quad*4 + r;
            float* obase = Op + ((size_t)z * 8192 + b * 2048 + q0 + row) * DM;
#pragma unroll
            for (int nt = 0; nt < 4; nt++)
                obase[64*w + 16*nt + l15] = oacc[mt][nt][r];
        }
}

// ---------------- Combine split partials: out = sum_z Op[z] / sum_z l[z] -------------------
__global__ __launch_bounds__(256) void reduce_kernel(const float* __restrict__ Op,
                                                     const float* __restrict__ lp,
                                                     float* __restrict__ out)
{
    const int g = blockIdx.x * 256 + threadIdx.x;    // 1,048,576 threads x float4
    const size_t e = (size_t)g * 4;
    const int row = g >> 7;
    float4 o = *reinterpret_cast<const float4*>(Op + e);
    float4 a = *reinterpret_cast<const float4*>(Op + 4194304 + e);
    const float l = lp[row] + lp[8192 + row];
    const float linv = 1.0f / l;
    o.x = (o.x + a.x) * linv;
    o.y = (o.y + a.y) * linv;
    o.z = (o.z + a.z) * linv;
    o.w = (o.w + a.w) * linv;
    *reinterpret_cast<float4*>(out + e) = o;
}

extern "C" void kernel_launch(void* const* d_in, const int* in_sizes, int n_in,
                              void* d_out, int out_size, void* d_ws, size_t ws_size,
                              hipStream_t stream)
{
    const float* x   = (const float*)d_in[0];
    const float* enc = (const float*)d_in[1];
    const float* wq  = (const float*)d_in[2];
    const float* bq  = (const float*)d_in[3];
    const float* wk  = (const float*)d_in[4];
    const float* bk  = (const float*)d_in[5];
    const float* wv  = (const float*)d_in[6];
    const float* bv  = (const float*)d_in[7];
    float* out = (float*)d_out;

    char* ws = (char*)d_ws;
    bf16*  Qb   = (bf16*)ws;
    bf16*  Kb   = (bf16*)(ws + 8388608);
    bf16*  Vtg  = (bf16*)(ws + 25165824);
    bf16*  xb   = (bf16*)(ws + 41943040);
    bf16*  encb = (bf16*)(ws + 50331648);
    bf16*  wqb  = (bf16*)(ws + 67108864);
    bf16*  wkb  = (bf16*)(ws + 67633152);
    bf16*  wvb  = (bf16*)(ws + 68157440);
    float* Op   = (float*)(ws + 41943040);          // overlaps xb/encb/w*b (phase 2)
    float* lp   = (float*)(ws + 41943040 + 2ull * 16777216);

    // prepass: fp32 -> bf16, single launch
    hipLaunchKernelGGL(cvt_all_kernel, dim3(6528), dim3(256), 0, stream,
                       x, xb, enc, encb, wq, wqb, wk, wkb, wv, wvb);

    // projections
    hipLaunchKernelGGL((proj_kernel<false>), dim3(8, 128), dim3(256), 0, stream,
                       xb, wqb, bq, Qb, (const bf16*)nullptr, (const float*)nullptr, (bf16*)nullptr);
    hipLaunchKernelGGL((proj_kernel<true>),  dim3(8, 256), dim3(256), 0, stream,
                       encb, wkb, bk, Kb, wvb, bv, Vtg);

    // attention (256 blocks x 512 threads, 1 block/CU) + combine
    hipLaunchKernelGGL(attn_kernel, dim3(256), dim3(512), 0, stream, Qb, Kb, Vtg, Op, lp);
    hipLaunchKernelGGL(reduce_kernel, dim3(4096), dim3(256), 0, stream, Op, lp, out);
}

// Round 6
// 241.954 us; speedup vs baseline: 1.4585x; 1.4585x over previous
//
#include <hip/hip_runtime.h>
#include <hip/hip_bf16.h>

// DecoderLayer cross-attention, MI355X/gfx950. Round 9.
// B=4, Sq=2048, Skv=4096, D=512. fp32 in/out, bf16 MFMA internally.
// R9 = R7 structure (af[16], 116 VGPR, no spill) + the three R8 components proven
// correct and spill-free:
//  - 4-bit XOR LDS swizzle (write: src lane^(row&15); read: off^(l15<<4)) --
//    R8 PROVED conflicts 9.4M -> 1.05M.
//  - vf (V frags) issued BEFORE K-DMA prefetch: compiler waits vf with counted vmcnt,
//    K-DMA stays in flight.
//  - mid-tile barrier = lgkmcnt(0)-only raw s_barrier (Ps is DS traffic); K-DMA
//    prefetch spans the whole tile, drained only by end-of-tile __syncthreads.
// R8's af[2][16] (128 VGPR Q) is DEAD: ArchVGPR cap 128 -> 25MB scratch spill traffic.
// ws layout:
//   Qb  bf16 [8192][512]          @ 0           (8,388,608)
//   Kb  bf16 [16384][512]         @ 8,388,608   (16,777,216)
//   Vtg bf16 [4][128][512][32]    @ 25,165,824  (16,777,216)   (t-tiled)
//   region B @ 41,943,040:
//     phase1: xb 8.4M | encb @+8.4M 16.8M | wqb/wkb/wvb @+25.2M 0.5M each
//     phase2: Op f32 [2][8192][512] | lp f32 [2][8192]  (need 75,563,008 B)

typedef __bf16 bf16;
typedef __attribute__((ext_vector_type(8))) __bf16 bf16x8;
typedef __attribute__((ext_vector_type(4))) float f32x4;

#define DM 512

__device__ __forceinline__ void gload_lds16(const bf16* g, bf16* l)
{
    __builtin_amdgcn_global_load_lds(
        (const __attribute__((address_space(1))) void*)g,
        (__attribute__((address_space(3))) void*)l, 16, 0, 0);
}

// ---------------- fp32 -> bf16 convert prepass (single launch, 5 regions) -----------------
__global__ __launch_bounds__(256) void cvt_all_kernel(
    const float* __restrict__ x,   bf16* __restrict__ xb,
    const float* __restrict__ enc, bf16* __restrict__ encb,
    const float* __restrict__ wq,  bf16* __restrict__ wqb,
    const float* __restrict__ wk,  bf16* __restrict__ wkb,
    const float* __restrict__ wv,  bf16* __restrict__ wvb)
{
    int g = blockIdx.x * 256 + threadIdx.x;
    const float* src; bf16* dst;
    if (g < 524288)       { src = x;   dst = xb; }
    else if (g < 1572864) { g -= 524288;  src = enc; dst = encb; }
    else if (g < 1605632) { g -= 1572864; src = wq;  dst = wqb; }
    else if (g < 1638400) { g -= 1605632; src = wk;  dst = wkb; }
    else                  { g -= 1638400; src = wv;  dst = wvb; }
    const float4 f0 = *reinterpret_cast<const float4*>(src + (size_t)g * 8);
    const float4 f1 = *reinterpret_cast<const float4*>(src + (size_t)g * 8 + 4);
    bf16x8 v;
    v[0]=(bf16)f0.x; v[1]=(bf16)f0.y; v[2]=(bf16)f0.z; v[3]=(bf16)f0.w;
    v[4]=(bf16)f1.x; v[5]=(bf16)f1.y; v[6]=(bf16)f1.z; v[7]=(bf16)f1.w;
    *reinterpret_cast<bf16x8*>(dst + (size_t)g * 8) = v;
}

// ---------------- Projection GEMMs (bf16 in): out = A @ W^T + b, stored bf16 ---------------
// KV=false: Q row-major. KV=true: K row-major + V t-tiled Vtg[b][t>>5][e][t&31].
template<bool KV>
__global__ __launch_bounds__(256) void proj_kernel(const bf16* __restrict__ A,
    const bf16* __restrict__ W0, const float* __restrict__ b0, bf16* __restrict__ out0,
    const bf16* __restrict__ W1, const float* __restrict__ b1, bf16* __restrict__ out1)
{
    __shared__ __align__(16) bf16 As[2][64][40];
    __shared__ __align__(16) bf16 W0s[2][64][40];
    __shared__ __align__(16) bf16 W1s[2][64][40];

    const int tid  = threadIdx.x;
    const int w    = tid >> 6, lane = tid & 63, quad = lane >> 4, l15 = lane & 15;
    const int wr   = w >> 1, wc = w & 1;
    const int n0   = blockIdx.x * 64;
    const int m0   = blockIdx.y * 64;
    const int srow = tid >> 2;
    const int scol = (tid & 3) * 8;

    f32x4 acc0[2][2] = {}, acc1[2][2] = {};
    bf16x8 ra, rw0, rw1;

    auto prefetch = [&](int kk) {
        ra  = *reinterpret_cast<const bf16x8*>(A  + (size_t)(m0 + srow) * DM + kk + scol);
        rw0 = *reinterpret_cast<const bf16x8*>(W0 + (size_t)(n0 + srow) * DM + kk + scol);
        if constexpr (KV)
            rw1 = *reinterpret_cast<const bf16x8*>(W1 + (size_t)(n0 + srow) * DM + kk + scol);
    };
    auto store_lds = [&](int p) {
        *reinterpret_cast<bf16x8*>(&As[p][srow][scol])  = ra;
        *reinterpret_cast<bf16x8*>(&W0s[p][srow][scol]) = rw0;
        if constexpr (KV)
            *reinterpret_cast<bf16x8*>(&W1s[p][srow][scol]) = rw1;
    };

    prefetch(0);
    store_lds(0);
    __syncthreads();

    for (int step = 0; step < 16; step++) {
        const int p = step & 1;
        if (step < 15) prefetch((step + 1) * 32);

        bf16x8 af[2], bf0[2], bf1[2];
#pragma unroll
        for (int mt = 0; mt < 2; mt++)
            af[mt] = *reinterpret_cast<const bf16x8*>(&As[p][32*wr + 16*mt + l15][quad*8]);
#pragma unroll
        for (int nt = 0; nt < 2; nt++)
            bf0[nt] = *reinterpret_cast<const bf16x8*>(&W0s[p][32*wc + 16*nt + l15][quad*8]);
        if constexpr (KV) {
#pragma unroll
            for (int nt = 0; nt < 2; nt++)
                bf1[nt] = *reinterpret_cast<const bf16x8*>(&W1s[p][32*wc + 16*nt + l15][quad*8]);
        }
#pragma unroll
        for (int mt = 0; mt < 2; mt++)
#pragma unroll
            for (int nt = 0; nt < 2; nt++) {
                acc0[mt][nt] = __builtin_amdgcn_mfma_f32_16x16x32_bf16(af[mt], bf0[nt], acc0[mt][nt], 0, 0, 0);
                if constexpr (KV)
                    acc1[mt][nt] = __builtin_amdgcn_mfma_f32_16x16x32_bf16(af[mt], bf1[nt], acc1[mt][nt], 0, 0, 0);
            }

        if (step < 15) store_lds(p ^ 1);
        __syncthreads();
    }

#pragma unroll
    for (int mt = 0; mt < 2; mt++)
#pragma unroll
        for (int nt = 0; nt < 2; nt++) {
            const int coll = 32*wc + 16*nt + l15;
            const int rowl = 32*wr + 16*mt + quad*4;
            {
                const float bv = b0[n0 + coll];
                f32x4 c = acc0[mt][nt];
#pragma unroll
                for (int r = 0; r < 4; r++)
                    out0[(size_t)(m0 + rowl + r) * DM + n0 + coll] = (bf16)(c[r] + bv);
            }
            if constexpr (KV) {
                const float bv = b1[n0 + coll];
                f32x4 c = acc1[mt][nt];
                const int gr = m0 + rowl;
                const int bidx = gr >> 12, t = gr & 4095;
                const int e = n0 + coll;
                union { uint2 u; bf16 h[4]; } pk;
#pragma unroll
                for (int r = 0; r < 4; r++) pk.h[r] = (bf16)(c[r] + bv);
                // t-tiled: Vtg[bidx][t>>5][e][t&31], t % 4 == 0 -> 4 contiguous elems
                *reinterpret_cast<uint2*>(out1 +
                    ((((size_t)(bidx*128 + (t >> 5)) * DM + e) << 5) + (t & 31))) = pk.u;
            }
        }
}

// ---------------- Fused attention: LDS-K (4-bit swz), reg-Q (16 rows/wave), reg-V ----------
// 512 threads / 8 waves, 1 block/CU, grid 256 = 1 round.
// QK: wave (qb=w>>1, cb0=2*(w&1)): S[16qb..+16][16cb0..+32]; A = Q regs af[16], B = Kt LDS.
// PV: wave w: O[64 q][64 e cols 64w..]; A = Ps LDS, B = V regs (t-tiled contiguous loads).
__global__ __launch_bounds__(512, 2) void attn_kernel(const bf16* __restrict__ Qb,
                                                      const bf16* __restrict__ Kb,
                                                      const bf16* __restrict__ Vtg,
                                                      float* __restrict__ Op,
                                                      float* __restrict__ lp)
{
    __shared__ __align__(16) bf16 Kt[2][64][512];   // 131,072 B; 4-bit XOR swizzle (src-side)
    __shared__ __align__(16) bf16 Ps[64][80];       //  10,240 B; 40 dw stride
    __shared__ float lred[64];

    const int tid  = threadIdx.x;
    const int w    = tid >> 6, lane = tid & 63, quad = lane >> 4, l15 = lane & 15;
    const int qb   = w >> 1;                 // QK q-row block 0..3
    const int cb0  = (w & 1) * 2;            // QK kv col blocks {cb0, cb0+1}

    // XCD-swizzle: 8 (b,z) combos map 1:1 onto 8 XCDs.
    const int id = blockIdx.x;               // 256 blocks
    const int combo = id & 7, qblk = id >> 3;
    const int b = combo & 3, z = combo >> 2;
    const int q0 = qblk * 64;
    const int NT = 32, tb = z * 2048;        // 32 tiles of 64 kv rows

    // ---- Q A-fragments into registers (once; 64 VGPR) ----
    bf16x8 af[16];
    {
        const bf16* qsrc = Qb + (size_t)(b*2048 + q0 + 16*qb + l15) * DM + quad*8;
#pragma unroll
        for (int k4 = 0; k4 < 16; k4++) af[k4] = *reinterpret_cast<const bf16x8*>(qsrc + k4*32);
    }
    if (tid < 64) lred[tid] = 0.f;

    const bf16* kbase = Kb + (size_t)(b*4096 + tb) * DM;
    // ---- stage K tile 0 (1 contiguous 1KB row/instr; source lane 4-bit XOR) ----
#pragma unroll
    for (int i = 0; i < 8; i++) {
        const int row = w + 8*i;             // row & 7 == w
        gload_lds16(kbase + (size_t)row * DM + ((lane ^ (row & 15)) * 8), &Kt[0][row][0]);
    }
    __syncthreads();                          // drains DMA, publishes lred

    f32x4 oacc[4][4] = {};
    float lsum[2][4] = {};
    const float kexp = 1.44269504088896f * 0.044194173824159216f;  // log2(e)/sqrt(512)
    const int sxor = l15 << 4;                // read-side 4-bit XOR (rows read have row&15==l15)

    for (int t = 0; t < NT; t++) {
        const int buf = t & 1;

        // V fragments for THIS tile first (oldest vmcnt -> vf-wait leaves K-DMA in flight)
        bf16x8 vf[4][2];
#pragma unroll
        for (int ks = 0; ks < 2; ks++) {
            const size_t tblk = (size_t)(b*128 + z*64 + t*2 + ks) * DM;
#pragma unroll
            for (int nt = 0; nt < 4; nt++)
                vf[nt][ks] = *reinterpret_cast<const bf16x8*>(
                    Vtg + ((tblk + 64*w + 16*nt + l15) << 5) + quad*8);
        }

        // prefetch next K tile (stays in flight until end-of-tile __syncthreads)
        if (t + 1 < NT) {
            const bf16* ksrc = kbase + (size_t)(t + 1) * 64 * DM;
#pragma unroll
            for (int i = 0; i < 8; i++) {
                const int row = w + 8*i;
                gload_lds16(ksrc + (size_t)row * DM + ((lane ^ (row & 15)) * 8), &Kt[buf ^ 1][row][0]);
            }
        }

        // ---- QK: S[16qb..+16][16(cb0..cb0+2)], A regs x B LDS ----
        f32x4 sacc[2] = {};
        const char* krowA = (const char*)&Kt[buf][16*cb0 + l15][0];
        const char* krowB = (const char*)&Kt[buf][16*cb0 + 16 + l15][0];
#pragma unroll
        for (int k4 = 0; k4 < 16; k4++) {
            const int off = (k4*64 + quad*16) ^ sxor;
            bf16x8 k0 = *reinterpret_cast<const bf16x8*>(krowA + off);
            bf16x8 k1 = *reinterpret_cast<const bf16x8*>(krowB + off);
            sacc[0] = __builtin_amdgcn_mfma_f32_16x16x32_bf16(af[k4], k0, sacc[0], 0, 0, 0);
            sacc[1] = __builtin_amdgcn_mfma_f32_16x16x32_bf16(af[k4], k1, sacc[1], 0, 0, 0);
        }

        // exp -> Ps (C-layout -> A-layout), accumulate l
#pragma unroll
        for (int s = 0; s < 2; s++)
#pragma unroll
            for (int r = 0; r < 4; r++) {
                const float p = exp2f(sacc[s][r] * kexp);
                lsum[s][r] += p;
                Ps[16*qb + quad*4 + r][16*(cb0 + s) + l15] = (bf16)p;
            }

        // mid-tile barrier: lgkm-only (Ps is DS traffic; keep K-DMA in flight)
        asm volatile("s_waitcnt lgkmcnt(0)" ::: "memory");
        __builtin_amdgcn_s_barrier();
        __builtin_amdgcn_sched_barrier(0);

        // ---- PV: O[64][64w..+64] += P[64][64] * V[64][...], A LDS x B regs ----
#pragma unroll
        for (int ks = 0; ks < 2; ks++) {
            bf16x8 ap[4];
#pragma unroll
            for (int mt = 0; mt < 4; mt++)
                ap[mt] = *reinterpret_cast<const bf16x8*>(&Ps[16*mt + l15][ks*32 + quad*8]);
#pragma unroll
            for (int nt = 0; nt < 4; nt++)
#pragma unroll
                for (int mt = 0; mt < 4; mt++)
                    oacc[mt][nt] = __builtin_amdgcn_mfma_f32_16x16x32_bf16(ap[mt], vf[nt][ks], oacc[mt][nt], 0, 0, 0);
        }
        __syncthreads();                      // protect Ps + publish K-DMA for next tile
    }

    // ---- epilogue: l reduction + O partial write ----
#pragma unroll
    for (int r = 0; r < 4; r++)
        atomicAdd(&lred[16*qb + quad*4 + r], lsum[0][r] + lsum[1][r]);
    __syncthreads();

    if (tid < 64) lp[(size_t)z * 8192 + b * 2048 + q0 + tid] = lred[tid];
#pragma unroll
    for (int mt = 0; mt < 4; mt++)
#pragma unroll
        for (int r = 0; r < 4; r++) {
            const int row = 16*mt + quad*4 + r;
            float* obase = Op + ((size_t)z * 8192 + b * 2048 + q0 + row) * DM;
#pragma unroll
            for (int nt = 0; nt < 4; nt++)
                obase[64*w + 16*nt + l15] = oacc[mt][nt][r];
        }
}

// ---------------- Combine split partials: out = sum_z Op[z] / sum_z l[z] -------------------
__global__ __launch_bounds__(256) void reduce_kernel(const float* __restrict__ Op,
                                                     const float* __restrict__ lp,
                                                     float* __restrict__ out)
{
    const int g = blockIdx.x * 256 + threadIdx.x;    // 1,048,576 threads x float4
    const size_t e = (size_t)g * 4;
    const int row = g >> 7;
    float4 o = *reinterpret_cast<const float4*>(Op + e);
    float4 a = *reinterpret_cast<const float4*>(Op + 4194304 + e);
    const float l = lp[row] + lp[8192 + row];
    const float linv = 1.0f / l;
    o.x = (o.x + a.x) * linv;
    o.y = (o.y + a.y) * linv;
    o.z = (o.z + a.z) * linv;
    o.w = (o.w + a.w) * linv;
    *reinterpret_cast<float4*>(out + e) = o;
}

extern "C" void kernel_launch(void* const* d_in, const int* in_sizes, int n_in,
                              void* d_out, int out_size, void* d_ws, size_t ws_size,
                              hipStream_t stream)
{
    const float* x   = (const float*)d_in[0];
    const float* enc = (const float*)d_in[1];
    const float* wq  = (const float*)d_in[2];
    const float* bq  = (const float*)d_in[3];
    const float* wk  = (const float*)d_in[4];
    const float* bk  = (const float*)d_in[5];
    const float* wv  = (const float*)d_in[6];
    const float* bv  = (const float*)d_in[7];
    float* out = (float*)d_out;

    char* ws = (char*)d_ws;
    bf16*  Qb   = (bf16*)ws;
    bf16*  Kb   = (bf16*)(ws + 8388608);
    bf16*  Vtg  = (bf16*)(ws + 25165824);
    bf16*  xb   = (bf16*)(ws + 41943040);
    bf16*  encb = (bf16*)(ws + 50331648);
    bf16*  wqb  = (bf16*)(ws + 67108864);
    bf16*  wkb  = (bf16*)(ws + 67633152);
    bf16*  wvb  = (bf16*)(ws + 68157440);
    float* Op   = (float*)(ws + 41943040);          // overlaps xb/encb/w*b (phase 2)
    float* lp   = (float*)(ws + 41943040 + 2ull * 16777216);

    // prepass: fp32 -> bf16, single launch
    hipLaunchKernelGGL(cvt_all_kernel, dim3(6528), dim3(256), 0, stream,
                       x, xb, enc, encb, wq, wqb, wk, wkb, wv, wvb);

    // projections
    hipLaunchKernelGGL((proj_kernel<false>), dim3(8, 128), dim3(256), 0, stream,
                       xb, wqb, bq, Qb, (const bf16*)nullptr, (const float*)nullptr, (bf16*)nullptr);
    hipLaunchKernelGGL((proj_kernel<true>),  dim3(8, 256), dim3(256), 0, stream,
                       encb, wkb, bk, Kb, wvb, bv, Vtg);

    // attention (256 blocks x 512 threads, 1 block/CU) + combine
    hipLaunchKernelGGL(attn_kernel, dim3(256), dim3(512), 0, stream, Qb, Kb, Vtg, Op, lp);
    hipLaunchKernelGGL(reduce_kernel, dim3(4096), dim3(256), 0, stream, Op, lp, out);
}

// Round 7
// 232.037 us; speedup vs baseline: 1.5208x; 1.0427x over previous
//
#include <hip/hip_runtime.h>
#include <hip/hip_bf16.h>

// DecoderLayer cross-attention, MI355X/gfx950. Round 10.
// B=4, Sq=2048, Skv=4096, D=512. fp32 in/out, bf16 MFMA internally.
// R10 changes vs R9 (attn now 94us; non-attn ~148us is the sink, proj ~110us @ ~195TF):
//  - proj kernels REWRITTEN in the m97 structure: 128x128 tile, BK=32, 4 waves (2x2),
//    4x4 16x16 frags/wave, double-buffered LDS via global_load_lds width-16
//    (1KB contiguous per instruction -- the R7-proven contiguous-burst principle),
//    2-bit XOR swizzle on 64B LDS rows (src-side write, XOR'd read; 4-way -> 2-way).
//  - attn / cvt / reduce byte-identical to R9 (attribution discipline).
// ws layout:
//   Qb  bf16 [8192][512]          @ 0           (8,388,608)
//   Kb  bf16 [16384][512]         @ 8,388,608   (16,777,216)
//   Vtg bf16 [4][128][512][32]    @ 25,165,824  (16,777,216)   (t-tiled)
//   region B @ 41,943,040:
//     phase1: xb 8.4M | encb @+8.4M 16.8M | wqb/wkb/wvb @+25.2M 0.5M each
//     phase2: Op f32 [2][8192][512] | lp f32 [2][8192]  (need 75,563,008 B)

typedef __bf16 bf16;
typedef __attribute__((ext_vector_type(8))) __bf16 bf16x8;
typedef __attribute__((ext_vector_type(4))) float f32x4;

#define DM 512

__device__ __forceinline__ void gload_lds16(const bf16* g, bf16* l)
{
    __builtin_amdgcn_global_load_lds(
        (const __attribute__((address_space(1))) void*)g,
        (__attribute__((address_space(3))) void*)l, 16, 0, 0);
}

// ---------------- fp32 -> bf16 convert prepass (single launch, 5 regions) -----------------
__global__ __launch_bounds__(256) void cvt_all_kernel(
    const float* __restrict__ x,   bf16* __restrict__ xb,
    const float* __restrict__ enc, bf16* __restrict__ encb,
    const float* __restrict__ wq,  bf16* __restrict__ wqb,
    const float* __restrict__ wk,  bf16* __restrict__ wkb,
    const float* __restrict__ wv,  bf16* __restrict__ wvb)
{
    int g = blockIdx.x * 256 + threadIdx.x;
    const float* src; bf16* dst;
    if (g < 524288)       { src = x;   dst = xb; }
    else if (g < 1572864) { g -= 524288;  src = enc; dst = encb; }
    else if (g < 1605632) { g -= 1572864; src = wq;  dst = wqb; }
    else if (g < 1638400) { g -= 1605632; src = wk;  dst = wkb; }
    else                  { g -= 1638400; src = wv;  dst = wvb; }
    const float4 f0 = *reinterpret_cast<const float4*>(src + (size_t)g * 8);
    const float4 f1 = *reinterpret_cast<const float4*>(src + (size_t)g * 8 + 4);
    bf16x8 v;
    v[0]=(bf16)f0.x; v[1]=(bf16)f0.y; v[2]=(bf16)f0.z; v[3]=(bf16)f0.w;
    v[4]=(bf16)f1.x; v[5]=(bf16)f1.y; v[6]=(bf16)f1.z; v[7]=(bf16)f1.w;
    *reinterpret_cast<bf16x8*>(dst + (size_t)g * 8) = v;
}

// ---------------- Projection GEMMs, m97 structure: out = A @ W^T + b, stored bf16 ----------
// 128x128 tile, BK=32, 256 threads (4 waves 2x2), dbuf LDS via global_load_lds (1KB/instr).
// LDS rows are 64B; 2-bit XOR swizzle: slot s of row r holds logical col-group s^(r&3);
// write side pre-swizzles the GLOBAL source column (linear LDS dest), read XORs the slot.
// KV=false: Q row-major. KV=true: K row-major + V t-tiled Vtg[b][t>>5][e][t&31].
template<bool KV>
__global__ __launch_bounds__(256, 2) void proj_kernel(const bf16* __restrict__ A,
    const bf16* __restrict__ W0, const float* __restrict__ b0, bf16* __restrict__ out0,
    const bf16* __restrict__ W1, const float* __restrict__ b1, bf16* __restrict__ out1)
{
    __shared__ __align__(16) bf16 As[2][128][32];
    __shared__ __align__(16) bf16 W0s[2][128][32];
    __shared__ __align__(16) bf16 W1s[2][128][32];   // eliminated by compiler when !KV

    const int tid  = threadIdx.x;
    const int w    = tid >> 6, lane = tid & 63, quad = lane >> 4, l15 = lane & 15;
    const int wr   = w >> 1, wc = w & 1;
    const int n0   = blockIdx.x * 128;
    const int m0   = blockIdx.y * 128;

    // staging source: lane covers row (lane>>2) within a 16-row segment, col-slot
    // (lane&3) of the 64B row; pre-swizzled source col = ((lane&3) ^ (row&3)) * 8.
    const int lrow = lane >> 2;
    const int scol = ((lane & 3) ^ (lrow & 3)) * 8;
    const bf16* aSrc  = A  + (size_t)(m0 + lrow) * DM + scol;
    const bf16* wSrc0 = W0 + (size_t)(n0 + lrow) * DM + scol;
    const bf16* wSrc1 = KV ? (W1 + (size_t)(n0 + lrow) * DM + scol) : nullptr;

    auto stage = [&](int p, int kk) {
#pragma unroll
        for (int j = 0; j < 2; j++) {
            const int seg = 2 * w + j;                  // 8 segments of 16 rows
            gload_lds16(aSrc  + (size_t)(16 * seg) * DM + kk, &As[p][16 * seg][0]);
            gload_lds16(wSrc0 + (size_t)(16 * seg) * DM + kk, &W0s[p][16 * seg][0]);
            if constexpr (KV)
                gload_lds16(wSrc1 + (size_t)(16 * seg) * DM + kk, &W1s[p][16 * seg][0]);
        }
    };

    f32x4 acc0[4][4] = {}, acc1[4][4] = {};
    const int sx = (l15 & 3);                           // read-side slot XOR (row&3 == l15&3)

    stage(0, 0);
    __syncthreads();

    for (int step = 0; step < 16; step++) {
        const int p = step & 1;
        if (step < 15) stage(p ^ 1, (step + 1) * 32);   // DMA overlaps this step's compute

        bf16x8 af[4];
#pragma unroll
        for (int mt = 0; mt < 4; mt++)
            af[mt] = *reinterpret_cast<const bf16x8*>(
                &As[p][64*wr + 16*mt + l15][(quad ^ sx) * 8]);
#pragma unroll
        for (int nt = 0; nt < 4; nt++) {
            bf16x8 w0f = *reinterpret_cast<const bf16x8*>(
                &W0s[p][64*wc + 16*nt + l15][(quad ^ sx) * 8]);
#pragma unroll
            for (int mt = 0; mt < 4; mt++)
                acc0[mt][nt] = __builtin_amdgcn_mfma_f32_16x16x32_bf16(af[mt], w0f, acc0[mt][nt], 0, 0, 0);
            if constexpr (KV) {
                bf16x8 w1f = *reinterpret_cast<const bf16x8*>(
                    &W1s[p][64*wc + 16*nt + l15][(quad ^ sx) * 8]);
#pragma unroll
                for (int mt = 0; mt < 4; mt++)
                    acc1[mt][nt] = __builtin_amdgcn_mfma_f32_16x16x32_bf16(af[mt], w1f, acc1[mt][nt], 0, 0, 0);
            }
        }
        __syncthreads();                                 // drains DMA + protects LDS reads
    }

#pragma unroll
    for (int mt = 0; mt < 4; mt++)
#pragma unroll
        for (int nt = 0; nt < 4; nt++) {
            const int coll = 64*wc + 16*nt + l15;
            const int rowl = 64*wr + 16*mt + quad*4;
            {
                const float bv = b0[n0 + coll];
                f32x4 c = acc0[mt][nt];
#pragma unroll
                for (int r = 0; r < 4; r++)
                    out0[(size_t)(m0 + rowl + r) * DM + n0 + coll] = (bf16)(c[r] + bv);
            }
            if constexpr (KV) {
                const float bv = b1[n0 + coll];
                f32x4 c = acc1[mt][nt];
                const int gr = m0 + rowl;
                const int bidx = gr >> 12, t = gr & 4095;
                const int e = n0 + coll;
                union { uint2 u; bf16 h[4]; } pk;
#pragma unroll
                for (int r = 0; r < 4; r++) pk.h[r] = (bf16)(c[r] + bv);
                // t-tiled: Vtg[bidx][t>>5][e][t&31], t % 4 == 0 -> 4 contiguous elems
                *reinterpret_cast<uint2*>(out1 +
                    ((((size_t)(bidx*128 + (t >> 5)) * DM + e) << 5) + (t & 31))) = pk.u;
            }
        }
}

// ---------------- Fused attention: LDS-K (4-bit swz), reg-Q (16 rows/wave), reg-V ----------
// (byte-identical to R9)
__global__ __launch_bounds__(512, 2) void attn_kernel(const bf16* __restrict__ Qb,
                                                      const bf16* __restrict__ Kb,
                                                      const bf16* __restrict__ Vtg,
                                                      float* __restrict__ Op,
                                                      float* __restrict__ lp)
{
    __shared__ __align__(16) bf16 Kt[2][64][512];   // 131,072 B; 4-bit XOR swizzle (src-side)
    __shared__ __align__(16) bf16 Ps[64][80];       //  10,240 B; 40 dw stride
    __shared__ float lred[64];

    const int tid  = threadIdx.x;
    const int w    = tid >> 6, lane = tid & 63, quad = lane >> 4, l15 = lane & 15;
    const int qb   = w >> 1;                 // QK q-row block 0..3
    const int cb0  = (w & 1) * 2;            // QK kv col blocks {cb0, cb0+1}

    // XCD-swizzle: 8 (b,z) combos map 1:1 onto 8 XCDs.
    const int id = blockIdx.x;               // 256 blocks
    const int combo = id & 7, qblk = id >> 3;
    const int b = combo & 3, z = combo >> 2;
    const int q0 = qblk * 64;
    const int NT = 32, tb = z * 2048;        // 32 tiles of 64 kv rows

    // ---- Q A-fragments into registers (once; 64 VGPR) ----
    bf16x8 af[16];
    {
        const bf16* qsrc = Qb + (size_t)(b*2048 + q0 + 16*qb + l15) * DM + quad*8;
#pragma unroll
        for (int k4 = 0; k4 < 16; k4++) af[k4] = *reinterpret_cast<const bf16x8*>(qsrc + k4*32);
    }
    if (tid < 64) lred[tid] = 0.f;

    const bf16* kbase = Kb + (size_t)(b*4096 + tb) * DM;
    // ---- stage K tile 0 (1 contiguous 1KB row/instr; source lane 4-bit XOR) ----
#pragma unroll
    for (int i = 0; i < 8; i++) {
        const int row = w + 8*i;             // row & 7 == w
        gload_lds16(kbase + (size_t)row * DM + ((lane ^ (row & 15)) * 8), &Kt[0][row][0]);
    }
    __syncthreads();                          // drains DMA, publishes lred

    f32x4 oacc[4][4] = {};
    float lsum[2][4] = {};
    const float kexp = 1.44269504088896f * 0.044194173824159216f;  // log2(e)/sqrt(512)
    const int sxor = l15 << 4;                // read-side 4-bit XOR (rows read have row&15==l15)

    for (int t = 0; t < NT; t++) {
        const int buf = t & 1;

        // V fragments for THIS tile first (oldest vmcnt -> vf-wait leaves K-DMA in flight)
        bf16x8 vf[4][2];
#pragma unroll
        for (int ks = 0; ks < 2; ks++) {
            const size_t tblk = (size_t)(b*128 + z*64 + t*2 + ks) * DM;
#pragma unroll
            for (int nt = 0; nt < 4; nt++)
                vf[nt][ks] = *reinterpret_cast<const bf16x8*>(
                    Vtg + ((tblk + 64*w + 16*nt + l15) << 5) + quad*8);
        }

        // prefetch next K tile (stays in flight until end-of-tile __syncthreads)
        if (t + 1 < NT) {
            const bf16* ksrc = kbase + (size_t)(t + 1) * 64 * DM;
#pragma unroll
            for (int i = 0; i < 8; i++) {
                const int row = w + 8*i;
                gload_lds16(ksrc + (size_t)row * DM + ((lane ^ (row & 15)) * 8), &Kt[buf ^ 1][row][0]);
            }
        }

        // ---- QK: S[16qb..+16][16(cb0..cb0+2)], A regs x B LDS ----
        f32x4 sacc[2] = {};
        const char* krowA = (const char*)&Kt[buf][16*cb0 + l15][0];
        const char* krowB = (const char*)&Kt[buf][16*cb0 + 16 + l15][0];
#pragma unroll
        for (int k4 = 0; k4 < 16; k4++) {
            const int off = (k4*64 + quad*16) ^ sxor;
            bf16x8 k0 = *reinterpret_cast<const bf16x8*>(krowA + off);
            bf16x8 k1 = *reinterpret_cast<const bf16x8*>(krowB + off);
            sacc[0] = __builtin_amdgcn_mfma_f32_16x16x32_bf16(af[k4], k0, sacc[0], 0, 0, 0);
            sacc[1] = __builtin_amdgcn_mfma_f32_16x16x32_bf16(af[k4], k1, sacc[1], 0, 0, 0);
        }

        // exp -> Ps (C-layout -> A-layout), accumulate l
#pragma unroll
        for (int s = 0; s < 2; s++)
#pragma unroll
            for (int r = 0; r < 4; r++) {
                const float p = exp2f(sacc[s][r] * kexp);
                lsum[s][r] += p;
                Ps[16*qb + quad*4 + r][16*(cb0 + s) + l15] = (bf16)p;
            }

        // mid-tile barrier: lgkm-only (Ps is DS traffic; keep K-DMA in flight)
        asm volatile("s_waitcnt lgkmcnt(0)" ::: "memory");
        __builtin_amdgcn_s_barrier();
        __builtin_amdgcn_sched_barrier(0);

        // ---- PV: O[64][64w..+64] += P[64][64] * V[64][...], A LDS x B regs ----
#pragma unroll
        for (int ks = 0; ks < 2; ks++) {
            bf16x8 ap[4];
#pragma unroll
            for (int mt = 0; mt < 4; mt++)
                ap[mt] = *reinterpret_cast<const bf16x8*>(&Ps[16*mt + l15][ks*32 + quad*8]);
#pragma unroll
            for (int nt = 0; nt < 4; nt++)
#pragma unroll
                for (int mt = 0; mt < 4; mt++)
                    oacc[mt][nt] = __builtin_amdgcn_mfma_f32_16x16x32_bf16(ap[mt], vf[nt][ks], oacc[mt][nt], 0, 0, 0);
        }
        __syncthreads();                      // protect Ps + publish K-DMA for next tile
    }

    // ---- epilogue: l reduction + O partial write ----
#pragma unroll
    for (int r = 0; r < 4; r++)
        atomicAdd(&lred[16*qb + quad*4 + r], lsum[0][r] + lsum[1][r]);
    __syncthreads();

    if (tid < 64) lp[(size_t)z * 8192 + b * 2048 + q0 + tid] = lred[tid];
#pragma unroll
    for (int mt = 0; mt < 4; mt++)
#pragma unroll
        for (int r = 0; r < 4; r++) {
            const int row = 16*mt + quad*4 + r;
            float* obase = Op + ((size_t)z * 8192 + b * 2048 + q0 + row) * DM;
#pragma unroll
            for (int nt = 0; nt < 4; nt++)
                obase[64*w + 16*nt + l15] = oacc[mt][nt][r];
        }
}

// ---------------- Combine split partials: out = sum_z Op[z] / sum_z l[z] -------------------
__global__ __launch_bounds__(256) void reduce_kernel(const float* __restrict__ Op,
                                                     const float* __restrict__ lp,
                                                     float* __restrict__ out)
{
    const int g = blockIdx.x * 256 + threadIdx.x;    // 1,048,576 threads x float4
    const size_t e = (size_t)g * 4;
    const int row = g >> 7;
    float4 o = *reinterpret_cast<const float4*>(Op + e);
    float4 a = *reinterpret_cast<const float4*>(Op + 4194304 + e);
    const float l = lp[row] + lp[8192 + row];
    const float linv = 1.0f / l;
    o.x = (o.x + a.x) * linv;
    o.y = (o.y + a.y) * linv;
    o.z = (o.z + a.z) * linv;
    o.w = (o.w + a.w) * linv;
    *reinterpret_cast<float4*>(out + e) = o;
}

extern "C" void kernel_launch(void* const* d_in, const int* in_sizes, int n_in,
                              void* d_out, int out_size, void* d_ws, size_t ws_size,
                              hipStream_t stream)
{
    const float* x   = (const float*)d_in[0];
    const float* enc = (const float*)d_in[1];
    const float* wq  = (const float*)d_in[2];
    const float* bq  = (const float*)d_in[3];
    const float* wk  = (const float*)d_in[4];
    const float* bk  = (const float*)d_in[5];
    const float* wv  = (const float*)d_in[6];
    const float* bv  = (const float*)d_in[7];
    float* out = (float*)d_out;

    char* ws = (char*)d_ws;
    bf16*  Qb   = (bf16*)ws;
    bf16*  Kb   = (bf16*)(ws + 8388608);
    bf16*  Vtg  = (bf16*)(ws + 25165824);
    bf16*  xb   = (bf16*)(ws + 41943040);
    bf16*  encb = (bf16*)(ws + 50331648);
    bf16*  wqb  = (bf16*)(ws + 67108864);
    bf16*  wkb  = (bf16*)(ws + 67633152);
    bf16*  wvb  = (bf16*)(ws + 68157440);
    float* Op   = (float*)(ws + 41943040);          // overlaps xb/encb/w*b (phase 2)
    float* lp   = (float*)(ws + 41943040 + 2ull * 16777216);

    // prepass: fp32 -> bf16, single launch
    hipLaunchKernelGGL(cvt_all_kernel, dim3(6528), dim3(256), 0, stream,
                       x, xb, enc, encb, wq, wqb, wk, wkb, wv, wvb);

    // projections (m97-structure 128x128 tiles)
    hipLaunchKernelGGL((proj_kernel<false>), dim3(4, 64), dim3(256), 0, stream,
                       xb, wqb, bq, Qb, (const bf16*)nullptr, (const float*)nullptr, (bf16*)nullptr);
    hipLaunchKernelGGL((proj_kernel<true>),  dim3(4, 128), dim3(256), 0, stream,
                       encb, wkb, bk, Kb, wvb, bv, Vtg);

    // attention (256 blocks x 512 threads, 1 block/CU) + combine
    hipLaunchKernelGGL(attn_kernel, dim3(256), dim3(512), 0, stream, Qb, Kb, Vtg, Op, lp);
    hipLaunchKernelGGL(reduce_kernel, dim3(4096), dim3(256), 0, stream, Op, lp, out);
}